// Round 1
// baseline (188.375 us; speedup 1.0000x reference)
//
#include <hip/hip_runtime.h>

typedef __attribute__((ext_vector_type(8))) __bf16 bf16x8;
typedef __attribute__((ext_vector_type(4))) float floatx4;

__device__ inline unsigned bf1(float a){
  unsigned u = __float_as_uint(a);
  return (u + 0x7FFFu + ((u >> 16) & 1u)) >> 16;   // RNE fp32->bf16 bits
}
__device__ inline unsigned bfpack(float lo, float hi){
  return bf1(lo) | (bf1(hi) << 16);
}

// LDS layout, ushort (bf16) indices. Rows padded 64 -> 72 elems (144 B = 36
// dwords: per-row bank offset 4 -> <=2-way conflicts on b128 frag reads, free).
#define LW2 0        // W2 as B-matrix [n=oc(32)][k=ic*2+kw(64)] : native W2 flat layout
#define LWP 2304     // Wp as B-matrix [n=o(64)][k(64)]          : native Wp flat layout
#define LA0 6912     // A0 [row(64)][ic*2+kw]  (h1 window w=0)
#define LA1 11520    // A1 [row(64)][ic*2+kw]  (h1 window w=1)
#define LH2 16128    // h2 [row(64)][oc*2+w]
// total 20736 ushort = 41472 B

__global__ __launch_bounds__(256) void cnn_fused(
    const float* __restrict__ x,  const float* __restrict__ W1,
    const float* __restrict__ b1, const float* __restrict__ W2,
    const float* __restrict__ b2, const float* __restrict__ Wp,
    const float* __restrict__ bp, float* __restrict__ out)
{
  __shared__ ushort lds[20736];
  unsigned* ldsu = (unsigned*)lds;
  const int tid = threadIdx.x;

  // Stage weights into LDS as bf16 (pads never read by frags: k < 64 always).
  for (int i = tid; i < 2048; i += 256) lds[LW2 + (i >> 6)*72 + (i & 63)] = (ushort)bf1(W2[i]);
  for (int i = tid; i < 4096; i += 256) lds[LWP + (i >> 6)*72 + (i & 63)] = (ushort)bf1(Wp[i]);

  const int rowbase = blockIdx.x * 64;
  const int rl  = tid & 63;    // row within block tile (phase 1)
  const int wid = tid >> 6;    // wave id; also oc-octet in phase 1
  const long r = rowbase + rl;

  // ---- Phase 1: conv1 in fp32 VALU, emit A0/A1 bf16 ----
  const float4 xa = ((const float4*)x)[2*r];      // x[h=0][w=0..3]
  const float4 xb = ((const float4*)x)[2*r + 1];  // x[h=1][w=0..3]

  #pragma unroll
  for (int i = 0; i < 8; ++i){
    const int oc = wid*8 + i;
    const float w00 = W1[oc*4+0], w01 = W1[oc*4+1];
    const float w10 = W1[oc*4+2], w11 = W1[oc*4+3];
    const float bb  = b1[oc];
    // h1[oc][w] = relu(b1 + w00*x0[w] + w01*x0[w+1] + w10*x1[w] + w11*x1[w+1])
    const float h0 = fmaxf(0.f, bb + w00*xa.x + w01*xa.y + w10*xb.x + w11*xb.y);
    const float h1 = fmaxf(0.f, bb + w00*xa.y + w01*xa.z + w10*xb.y + w11*xb.z);
    const float h2 = fmaxf(0.f, bb + w00*xa.z + w01*xa.w + w10*xb.z + w11*xb.w);
    ldsu[(LA0 + rl*72 + oc*2) >> 1] = bfpack(h0, h1);  // A0[r][oc*2+{0,1}]
    ldsu[(LA1 + rl*72 + oc*2) >> 1] = bfpack(h1, h2);  // A1[r][oc*2+{0,1}]
  }
  __syncthreads();

  // ---- Stage B: conv2 as two K=64 GEMMs (shared B = W2), MFMA bf16 ----
  const int lane = tid & 63, lm = lane & 15, quad = lane >> 4;
  const int arow = (wid*16 + lm)*72;

  bf16x8 a0k0 = *(const bf16x8*)&lds[LA0 + arow +      quad*8];
  bf16x8 a0k1 = *(const bf16x8*)&lds[LA0 + arow + 32 + quad*8];
  bf16x8 a1k0 = *(const bf16x8*)&lds[LA1 + arow +      quad*8];
  bf16x8 a1k1 = *(const bf16x8*)&lds[LA1 + arow + 32 + quad*8];

  bf16x8 b0k0 = *(const bf16x8*)&lds[LW2 + (lm)*72      +      quad*8];
  bf16x8 b0k1 = *(const bf16x8*)&lds[LW2 + (lm)*72      + 32 + quad*8];
  bf16x8 b1k0 = *(const bf16x8*)&lds[LW2 + (16+lm)*72   +      quad*8];
  bf16x8 b1k1 = *(const bf16x8*)&lds[LW2 + (16+lm)*72   + 32 + quad*8];

  floatx4 z = {0.f, 0.f, 0.f, 0.f};
  floatx4 acc00 = z, acc01 = z, acc10 = z, acc11 = z;  // acc[gemm][ntile]
  acc00 = __builtin_amdgcn_mfma_f32_16x16x32_bf16(a0k0, b0k0, acc00, 0,0,0);
  acc00 = __builtin_amdgcn_mfma_f32_16x16x32_bf16(a0k1, b0k1, acc00, 0,0,0);
  acc01 = __builtin_amdgcn_mfma_f32_16x16x32_bf16(a0k0, b1k0, acc01, 0,0,0);
  acc01 = __builtin_amdgcn_mfma_f32_16x16x32_bf16(a0k1, b1k1, acc01, 0,0,0);
  acc10 = __builtin_amdgcn_mfma_f32_16x16x32_bf16(a1k0, b0k0, acc10, 0,0,0);
  acc10 = __builtin_amdgcn_mfma_f32_16x16x32_bf16(a1k1, b0k1, acc10, 0,0,0);
  acc11 = __builtin_amdgcn_mfma_f32_16x16x32_bf16(a1k0, b1k0, acc11, 0,0,0);
  acc11 = __builtin_amdgcn_mfma_f32_16x16x32_bf16(a1k1, b1k1, acc11, 0,0,0);

  // Epilogue B: +b2, relu, pack (w=0,w=1) -> h2[row][oc*2+w]
  const float b2a = b2[lm], b2b = b2[16 + lm];
  #pragma unroll
  for (int rg = 0; rg < 4; ++rg){
    const int m = wid*16 + quad*4 + rg;   // D row = batch row (m89 layout)
    ldsu[(LH2 + m*72 + lm*2) >> 1] =
        bfpack(fmaxf(0.f, acc00[rg] + b2a), fmaxf(0.f, acc10[rg] + b2a));
    ldsu[(LH2 + m*72 + (16+lm)*2) >> 1] =
        bfpack(fmaxf(0.f, acc01[rg] + b2b), fmaxf(0.f, acc11[rg] + b2b));
  }
  __syncthreads();

  // ---- Stage C: out = h2 @ Wp^T + bp, K=64, N=64 ----
  bf16x8 ca0 = *(const bf16x8*)&lds[LH2 + arow +      quad*8];
  bf16x8 ca1 = *(const bf16x8*)&lds[LH2 + arow + 32 + quad*8];

  floatx4 oacc[4];
  #pragma unroll
  for (int t = 0; t < 4; ++t){
    bf16x8 wb0 = *(const bf16x8*)&lds[LWP + (t*16+lm)*72 +      quad*8];
    bf16x8 wb1 = *(const bf16x8*)&lds[LWP + (t*16+lm)*72 + 32 + quad*8];
    floatx4 acc = z;
    acc = __builtin_amdgcn_mfma_f32_16x16x32_bf16(ca0, wb0, acc, 0,0,0);
    acc = __builtin_amdgcn_mfma_f32_16x16x32_bf16(ca1, wb1, acc, 0,0,0);
    oacc[t] = acc;
  }

  #pragma unroll
  for (int t = 0; t < 4; ++t){
    const float bpv = bp[t*16 + lm];
    #pragma unroll
    for (int rg = 0; rg < 4; ++rg){
      const int m = wid*16 + quad*4 + rg;
      out[(long)(rowbase + m)*64 + t*16 + lm] = oacc[t][rg] + bpv;
    }
  }
}

extern "C" void kernel_launch(void* const* d_in, const int* in_sizes, int n_in,
                              void* d_out, int out_size, void* d_ws, size_t ws_size,
                              hipStream_t stream)
{
  const float* x  = (const float*)d_in[0];
  const float* W1 = (const float*)d_in[1];
  const float* b1 = (const float*)d_in[2];
  const float* W2 = (const float*)d_in[3];
  const float* b2 = (const float*)d_in[4];
  const float* Wp = (const float*)d_in[5];
  const float* bp = (const float*)d_in[6];
  float* out = (float*)d_out;

  const int rows   = in_sizes[0] / 8;   // B*S = 524288
  const int blocks = rows / 64;         // 8192, exact
  cnn_fused<<<blocks, 256, 0, stream>>>(x, W1, b1, W2, b2, Wp, bp, out);
}

// Round 3
// 180.266 us; speedup vs baseline: 1.0450x; 1.0450x over previous
//
#include <hip/hip_runtime.h>

typedef __attribute__((ext_vector_type(8))) __bf16 bf16x8;
typedef __attribute__((ext_vector_type(8))) ushort ushort8;
typedef __attribute__((ext_vector_type(4))) float floatx4;

union FragU { ushort8 u; bf16x8 b; };

__device__ inline ushort bf1(float a){
  unsigned u = __float_as_uint(a);
  return (ushort)((u + 0x7FFFu + ((u >> 16) & 1u)) >> 16);   // RNE fp32->bf16
}
__device__ inline unsigned bfpack(float lo, float hi){
  return (unsigned)bf1(lo) | ((unsigned)bf1(hi) << 16);
}

#define BLOCKS 1024

// Per-wave pipeline (4 independent waves/block), weights in register frags:
//   conv1 fp32 VALU -> A-frags F0/F1/F2 (k-order kw*32+ic)
//   conv2 = 2 GEMMs K=64 via 8 MFMA (W2 B-frags in VGPR)
//   h2 transpose via per-wave LDS slice (C-layout -> A-layout),
//     packed cols c = w*32 + 2*(oc2&15) + (oc2>>4)
//   linear K=64 via 8 MFMA (Wp B-frags in VGPR, N-permuted so lane lm
//     owns out cols 4*lm..4*lm+3) -> float4 coalesced stores
__global__ __launch_bounds__(256) void cnn_fused(
    const float* __restrict__ x,  const float* __restrict__ W1,
    const float* __restrict__ b1, const float* __restrict__ W2,
    const float* __restrict__ b2, const float* __restrict__ Wp,
    const float* __restrict__ bp, float* __restrict__ out, int niter)
{
  __shared__ __align__(16) ushort h2buf[4 * 16 * 72];  // 9216 B
  const int tid  = threadIdx.x;
  const int wid  = tid >> 6;
  const int lane = tid & 63;
  const int lm   = lane & 15;
  const int quad = lane >> 4;
  ushort*   myh2 = &h2buf[wid * (16 * 72)];
  unsigned* h2d  = (unsigned*)myh2;                    // dword view, row stride 36

  // ---- loop-invariant register fragments ----
  // conv2 B-frags: lane supplies B[k = h*32 + quad*8+j][n = tt*16+lm],
  // k-order kw*32+ic  ->  W2 flat [oc2][ic][kw] index = oc2*64 + ic*2 + kw
  FragU w2f[2][2];   // [oc2-tile][k-half]
  #pragma unroll
  for (int t = 0; t < 2; ++t)
    #pragma unroll
    for (int h = 0; h < 2; ++h)
      #pragma unroll
      for (int j = 0; j < 8; ++j)
        w2f[t][h].u[j] = bf1(W2[(t*16 + lm)*64 + (quad*8 + j)*2 + h]);

  // linear B-frags: out col o = 4*lm + t; storage col c = h*32 + quad*8 + j;
  // c -> (w = c>>5, oc2 = ((c&31)>>1) | ((c&1)<<4)); Wp flat = o*64 + oc2*2 + w
  FragU wpf[4][2];   // [t = o%4][k-half]
  #pragma unroll
  for (int t = 0; t < 4; ++t)
    #pragma unroll
    for (int h = 0; h < 2; ++h)
      #pragma unroll
      for (int j = 0; j < 8; ++j){
        const int c   = h*32 + quad*8 + j;
        const int cp  = c & 31;
        const int oc2 = (cp >> 1) | ((cp & 1) << 4);
        wpf[t][h].u[j] = bf1(Wp[(4*lm + t)*64 + oc2*2 + h]);
      }

  // conv1 weights for ic = quad*8..quad*8+7 (this lane's A-frag k-range)
  float w1r[8][4], b1r[8];
  #pragma unroll
  for (int i = 0; i < 8; ++i){
    const int oc = quad*8 + i;
    w1r[i][0] = W1[oc*4+0]; w1r[i][1] = W1[oc*4+1];
    w1r[i][2] = W1[oc*4+2]; w1r[i][3] = W1[oc*4+3];
    b1r[i]    = b1[oc];
  }
  const float  b2a = b2[lm], b2b = b2[16 + lm];
  const float4 bp4 = ((const float4*)bp)[lm];          // bp[4*lm .. 4*lm+3]

  // ---- per-wave contiguous row range ----
  const long gw   = (long)blockIdx.x * 4 + wid;
  long tilebase   = gw * ((long)niter * 16);

  const float4* x4 = (const float4*)x;
  float4 xa = x4[2*(tilebase + lm)];
  float4 xb = x4[2*(tilebase + lm) + 1];

  const floatx4 z = {0.f, 0.f, 0.f, 0.f};

  for (int it = 0; it < niter; ++it){
    // prefetch next tile's x
    float4 nxa, nxb;
    if (it + 1 < niter){
      const long nr = tilebase + 16 + lm;
      nxa = x4[2*nr]; nxb = x4[2*nr + 1];
    }

    // ---- conv1 (fp32): rows lm, ic = quad*8+i, 3 windows ----
    FragU F0, F1, F2;
    #pragma unroll
    for (int i = 0; i < 8; ++i){
      const float w00 = w1r[i][0], w01 = w1r[i][1];
      const float w10 = w1r[i][2], w11 = w1r[i][3], bb = b1r[i];
      F0.u[i] = bf1(fmaxf(0.f, bb + w00*xa.x + w01*xa.y + w10*xb.x + w11*xb.y));
      F1.u[i] = bf1(fmaxf(0.f, bb + w00*xa.y + w01*xa.z + w10*xb.y + w11*xb.z));
      F2.u[i] = bf1(fmaxf(0.f, bb + w00*xa.z + w01*xa.w + w10*xb.z + w11*xb.w));
    }

    // ---- conv2: acc[g][tt], g = out window (w), tt = oc2-tile ----
    floatx4 a00 = z, a01 = z, a10 = z, a11 = z;
    a00 = __builtin_amdgcn_mfma_f32_16x16x32_bf16(F0.b, w2f[0][0].b, a00, 0,0,0);
    a00 = __builtin_amdgcn_mfma_f32_16x16x32_bf16(F1.b, w2f[0][1].b, a00, 0,0,0);
    a01 = __builtin_amdgcn_mfma_f32_16x16x32_bf16(F0.b, w2f[1][0].b, a01, 0,0,0);
    a01 = __builtin_amdgcn_mfma_f32_16x16x32_bf16(F1.b, w2f[1][1].b, a01, 0,0,0);
    a10 = __builtin_amdgcn_mfma_f32_16x16x32_bf16(F1.b, w2f[0][0].b, a10, 0,0,0);
    a10 = __builtin_amdgcn_mfma_f32_16x16x32_bf16(F2.b, w2f[0][1].b, a10, 0,0,0);
    a11 = __builtin_amdgcn_mfma_f32_16x16x32_bf16(F1.b, w2f[1][0].b, a11, 0,0,0);
    a11 = __builtin_amdgcn_mfma_f32_16x16x32_bf16(F2.b, w2f[1][1].b, a11, 0,0,0);

    // ---- epilogue conv2 -> h2 LDS (packed dwords, cols per mapping above) ----
    #pragma unroll
    for (int rg = 0; rg < 4; ++rg){
      const int rr = (quad*4 + rg) * 36;
      h2d[rr +      lm] = bfpack(fmaxf(0.f, a00[rg] + b2a), fmaxf(0.f, a01[rg] + b2b));
      h2d[rr + 16 + lm] = bfpack(fmaxf(0.f, a10[rg] + b2a), fmaxf(0.f, a11[rg] + b2b));
    }
    __syncthreads();

    // ---- stage C A-frags: row lm, k-halves ----
    FragU ca0, ca1;
    ca0.u = *(const ushort8*)&myh2[lm*72 +      quad*8];
    ca1.u = *(const ushort8*)&myh2[lm*72 + 32 + quad*8];

    // ---- linear: 4 N-tiles (t = o%4) ----
    floatx4 oacc[4];
    #pragma unroll
    for (int t = 0; t < 4; ++t){
      floatx4 acc = z;
      acc = __builtin_amdgcn_mfma_f32_16x16x32_bf16(ca0.b, wpf[t][0].b, acc, 0,0,0);
      acc = __builtin_amdgcn_mfma_f32_16x16x32_bf16(ca1.b, wpf[t][1].b, acc, 0,0,0);
      oacc[t] = acc;
    }

    // ---- coalesced float4 stores: lane lm owns cols 4*lm..4*lm+3 ----
    #pragma unroll
    for (int rg = 0; rg < 4; ++rg){
      float4 v;
      v.x = oacc[0][rg] + bp4.x;
      v.y = oacc[1][rg] + bp4.y;
      v.z = oacc[2][rg] + bp4.z;
      v.w = oacc[3][rg] + bp4.w;
      *(float4*)(out + (tilebase + quad*4 + rg)*64 + 4*lm) = v;
    }
    __syncthreads();

    if (it + 1 < niter){ xa = nxa; xb = nxb; tilebase += 16; }
  }
}

extern "C" void kernel_launch(void* const* d_in, const int* in_sizes, int n_in,
                              void* d_out, int out_size, void* d_ws, size_t ws_size,
                              hipStream_t stream)
{
  const float* x  = (const float*)d_in[0];
  const float* W1 = (const float*)d_in[1];
  const float* b1 = (const float*)d_in[2];
  const float* W2 = (const float*)d_in[3];
  const float* b2 = (const float*)d_in[4];
  const float* Wp = (const float*)d_in[5];
  const float* bp = (const float*)d_in[6];
  float* out = (float*)d_out;

  const int rows  = in_sizes[0] / 8;            // B*S = 524288
  const int tiles = rows / 16;                  // 32768 wave-tiles
  const int niter = tiles / (BLOCKS * 4);       // 8
  cnn_fused<<<BLOCKS, 256, 0, stream>>>(x, W1, b1, W2, b2, Wp, bp, out, niter);
}